// Round 5
// baseline (773.393 us; speedup 1.0000x reference)
//
#include <hip/hip_runtime.h>
#include <math.h>
#include <stdint.h>

#define N_TOK   8192      // B*S = 4*2048
#define DMODEL  1024
#define DCODEX  64
#define KCODES  8192

typedef short short8 __attribute__((ext_vector_type(8)));
typedef float f32x16 __attribute__((ext_vector_type(16)));

union Frag { short8 s; uint2 u[2]; };

// fp32 -> bf16 RNE, and back
__device__ __forceinline__ unsigned short f2bf(float f) {
    unsigned u = __float_as_uint(f);
    unsigned r = u + 0x7FFFu + ((u >> 16) & 1u);
    return (unsigned short)(r >> 16);
}
__device__ __forceinline__ float bf2f(unsigned short h) {
    return __uint_as_float(((unsigned)h) << 16);
}

// ---------------------------------------------------------------------------
// cn2[k] = sum_d codex[k][d]^2
__global__ __launch_bounds__(256) void codenorm_kernel(const float* __restrict__ codex,
                                                       float* __restrict__ cn2) {
    int k = blockIdx.x * 256 + threadIdx.x;
    const float4* p = (const float4*)(codex + (size_t)k * DCODEX);
    float s = 0.f;
#pragma unroll
    for (int i = 0; i < 16; ++i) {
        float4 v = p[i];
        s += v.x * v.x + v.y * v.y + v.z * v.z + v.w * v.w;
    }
    cn2[k] = s;
}

// ---------------------------------------------------------------------------
// Flat 3-way bf16 split: src[i] -> hi/mid/lo planes (row-major preserved).
// 4 floats per thread.
__global__ __launch_bounds__(256) void split3_kernel(const float* __restrict__ src,
                                                     unsigned short* __restrict__ p0,
                                                     unsigned short* __restrict__ p1,
                                                     unsigned short* __restrict__ p2) {
    size_t i4 = ((size_t)blockIdx.x * 256 + threadIdx.x) * 4;
    float4 v = *(const float4*)(src + i4);
    float f[4] = {v.x, v.y, v.z, v.w};
    ushort4 h0, h1, h2;
#pragma unroll
    for (int c = 0; c < 4; ++c) {
        unsigned short a0 = f2bf(f[c]);
        float r1 = f[c] - bf2f(a0);
        unsigned short a1 = f2bf(r1);
        float r2 = r1 - bf2f(a1);
        unsigned short a2 = f2bf(r2);
        ((unsigned short*)&h0)[c] = a0;
        ((unsigned short*)&h1)[c] = a1;
        ((unsigned short*)&h2)[c] = a2;
    }
    *(ushort4*)(p0 + i4) = h0;
    *(ushort4*)(p1 + i4) = h1;
    *(ushort4*)(p2 + i4) = h2;
}

// ---------------------------------------------------------------------------
// Split W1 (k x n, fp32) into 3 transposed bf16 planes W1t_l[n][k] (hi/mid/lo).
__global__ __launch_bounds__(256) void split_w1_kernel(const float* __restrict__ W1,
                                                       unsigned short* __restrict__ t0,
                                                       unsigned short* __restrict__ t1,
                                                       unsigned short* __restrict__ t2) {
    __shared__ float tile[32][33];
    const int tid = threadIdx.x;
    const int k0 = blockIdx.x * 32;
    const int n0 = blockIdx.y * 32;
    {
        int i = tid >> 3, j4 = (tid & 7) * 4;
        float4 v = *(const float4*)(W1 + (size_t)(k0 + i) * DMODEL + n0 + j4);
        tile[i][j4 + 0] = v.x; tile[i][j4 + 1] = v.y;
        tile[i][j4 + 2] = v.z; tile[i][j4 + 3] = v.w;
    }
    __syncthreads();
    int n = tid >> 3, kq = (tid & 7) * 4;
    ushort4 h0, h1, h2;
#pragma unroll
    for (int c = 0; c < 4; ++c) {
        float f = tile[kq + c][n];
        unsigned short a0 = f2bf(f);
        float r1 = f - bf2f(a0);
        unsigned short a1 = f2bf(r1);
        float r2 = r1 - bf2f(a1);
        unsigned short a2 = f2bf(r2);
        ((unsigned short*)&h0)[c] = a0;
        ((unsigned short*)&h1)[c] = a1;
        ((unsigned short*)&h2)[c] = a2;
    }
    size_t off = (size_t)(n0 + n) * DMODEL + k0 + kq;
    *(ushort4*)(t0 + off) = h0;
    *(ushort4*)(t1 + off) = h1;
    *(ushort4*)(t2 + off) = h2;
}

// ---------------------------------------------------------------------------
// H = tanh(Z @ W1 + b1) via bf16x6 MFMA; A and B both pre-split bf16 planes.
// 128x128 block tile, 4 waves 2x2, 64x64/wave (2x2 of 32x32x16).
__global__ __launch_bounds__(256) void gemm1_mfma_kernel(const unsigned short* __restrict__ Zt0,
                                                         const unsigned short* __restrict__ Zt1,
                                                         const unsigned short* __restrict__ Zt2,
                                                         const unsigned short* __restrict__ W1t0,
                                                         const unsigned short* __restrict__ W1t1,
                                                         const unsigned short* __restrict__ W1t2,
                                                         const float* __restrict__ b1,
                                                         float* __restrict__ H) {
    __shared__ unsigned short Ash[3][128][36];   // [level][m][k] pitch 36
    __shared__ unsigned short Bsh[3][128][36];   // [level][n][k] pitch 36
    const int tid = threadIdx.x;
    const int row0 = blockIdx.x * 128;
    const int col0 = blockIdx.y * 128;
    const int wave = tid >> 6;
    const int lane = tid & 63;
    const int lrow = lane & 31;
    const int lhalf = lane >> 5;
    const int wm = wave >> 1, wn = wave & 1;

    const unsigned short* Ap[3] = {Zt0, Zt1, Zt2};
    const unsigned short* Bp[3] = {W1t0, W1t1, W1t2};

    f32x16 acc[2][2];
#pragma unroll
    for (int i = 0; i < 2; ++i)
#pragma unroll
        for (int j = 0; j < 2; ++j)
#pragma unroll
            for (int r = 0; r < 16; ++r) acc[i][j][r] = 0.f;

    for (int k0 = 0; k0 < DMODEL; k0 += 32) {
        __syncthreads();   // WAR on Ash/Bsh
        // stage A & B: per plane 128 rows x 32 k bf16 = 512 uint4, 2/thread
#pragma unroll
        for (int l = 0; l < 3; ++l) {
#pragma unroll
            for (int t = 0; t < 2; ++t) {
                int q = tid + t * 256;
                int r = q >> 2, kq = (q & 3) * 8;
                uint4 va = *(const uint4*)(Ap[l] + (size_t)(row0 + r) * DMODEL + k0 + kq);
                *(uint2*)&Ash[l][r][kq]     = make_uint2(va.x, va.y);
                *(uint2*)&Ash[l][r][kq + 4] = make_uint2(va.z, va.w);
                uint4 vb = *(const uint4*)(Bp[l] + (size_t)(col0 + r) * DMODEL + k0 + kq);
                *(uint2*)&Bsh[l][r][kq]     = make_uint2(vb.x, vb.y);
                *(uint2*)&Bsh[l][r][kq + 4] = make_uint2(vb.z, vb.w);
            }
        }
        __syncthreads();
#pragma unroll
        for (int mk = 0; mk < 2; ++mk) {
            const int kb = mk * 16 + lhalf * 8;
            Frag ah[2], am[2], al[2], bh[2], bm[2], bl[2];
#pragma unroll
            for (int ti = 0; ti < 2; ++ti) {
                int rA = wm * 64 + ti * 32 + lrow;
                ah[ti].u[0] = *(const uint2*)&Ash[0][rA][kb];
                ah[ti].u[1] = *(const uint2*)&Ash[0][rA][kb + 4];
                am[ti].u[0] = *(const uint2*)&Ash[1][rA][kb];
                am[ti].u[1] = *(const uint2*)&Ash[1][rA][kb + 4];
                al[ti].u[0] = *(const uint2*)&Ash[2][rA][kb];
                al[ti].u[1] = *(const uint2*)&Ash[2][rA][kb + 4];
            }
#pragma unroll
            for (int tj = 0; tj < 2; ++tj) {
                int rB = wn * 64 + tj * 32 + lrow;
                bh[tj].u[0] = *(const uint2*)&Bsh[0][rB][kb];
                bh[tj].u[1] = *(const uint2*)&Bsh[0][rB][kb + 4];
                bm[tj].u[0] = *(const uint2*)&Bsh[1][rB][kb];
                bm[tj].u[1] = *(const uint2*)&Bsh[1][rB][kb + 4];
                bl[tj].u[0] = *(const uint2*)&Bsh[2][rB][kb];
                bl[tj].u[1] = *(const uint2*)&Bsh[2][rB][kb + 4];
            }
#pragma unroll
            for (int ti = 0; ti < 2; ++ti)
#pragma unroll
                for (int tj = 0; tj < 2; ++tj) {
                    acc[ti][tj] = __builtin_amdgcn_mfma_f32_32x32x16_bf16(ah[ti].s, bh[tj].s, acc[ti][tj], 0, 0, 0);
                    acc[ti][tj] = __builtin_amdgcn_mfma_f32_32x32x16_bf16(ah[ti].s, bm[tj].s, acc[ti][tj], 0, 0, 0);
                    acc[ti][tj] = __builtin_amdgcn_mfma_f32_32x32x16_bf16(am[ti].s, bh[tj].s, acc[ti][tj], 0, 0, 0);
                    acc[ti][tj] = __builtin_amdgcn_mfma_f32_32x32x16_bf16(am[ti].s, bm[tj].s, acc[ti][tj], 0, 0, 0);
                    acc[ti][tj] = __builtin_amdgcn_mfma_f32_32x32x16_bf16(ah[ti].s, bl[tj].s, acc[ti][tj], 0, 0, 0);
                    acc[ti][tj] = __builtin_amdgcn_mfma_f32_32x32x16_bf16(al[ti].s, bh[tj].s, acc[ti][tj], 0, 0, 0);
                }
        }
    }

    float b1v[2];
#pragma unroll
    for (int tj = 0; tj < 2; ++tj) b1v[tj] = b1[col0 + wn * 64 + tj * 32 + lrow];
#pragma unroll
    for (int ti = 0; ti < 2; ++ti)
#pragma unroll
        for (int tj = 0; tj < 2; ++tj) {
            int col = col0 + wn * 64 + tj * 32 + lrow;
#pragma unroll
            for (int r = 0; r < 16; ++r) {
                int row = row0 + wm * 64 + ti * 32 + (r & 3) + 8 * (r >> 2) + 4 * lhalf;
                H[(size_t)row * DMODEL + col] = tanhf(acc[ti][tj][r] + b1v[tj]);
            }
        }
}

// ---------------------------------------------------------------------------
// E = H @ W2 + b2 ; Ze = E / max(||E||_row, 1e-12)
__global__ __launch_bounds__(256) void gemm2_norm_kernel(const float* __restrict__ H,
                                                         const float* __restrict__ W2,
                                                         const float* __restrict__ b2,
                                                         float* __restrict__ Ze) {
    __shared__ float As[64][36];   // As[k][m] transposed
    __shared__ float Bs[64][68];   // Bs[k][n]
    const int tid = threadIdx.x;
    const int row0 = blockIdx.x * 32;
    const int ty = tid >> 4, tx = tid & 15;

    float acc[2][4];
#pragma unroll
    for (int i = 0; i < 2; ++i)
#pragma unroll
        for (int j = 0; j < 4; ++j) acc[i][j] = 0.f;

    for (int k0 = 0; k0 < DMODEL; k0 += 64) {
        __syncthreads();   // WAR
#pragma unroll
        for (int t = 0; t < 2; ++t) {
            int q = tid + t * 256;
            int r = q >> 4, k4 = (q & 15) * 4;
            float4 v = *(const float4*)(H + (size_t)(row0 + r) * DMODEL + k0 + k4);
            As[k4 + 0][r] = v.x; As[k4 + 1][r] = v.y;
            As[k4 + 2][r] = v.z; As[k4 + 3][r] = v.w;
        }
#pragma unroll
        for (int t = 0; t < 4; ++t) {
            int q = tid + t * 256;
            int kk = q >> 4, c4 = (q & 15) * 4;
            *(float4*)&Bs[kk][c4] = *(const float4*)(W2 + (size_t)(k0 + kk) * DCODEX + c4);
        }
        __syncthreads();
#pragma unroll
        for (int k = 0; k < 64; ++k) {
            float2 a = *(const float2*)&As[k][ty * 2];
            float4 b = *(const float4*)&Bs[k][tx * 4];
            float bw[4] = {b.x, b.y, b.z, b.w};
#pragma unroll
            for (int j = 0; j < 4; ++j) {
                acc[0][j] = fmaf(a.x, bw[j], acc[0][j]);
                acc[1][j] = fmaf(a.y, bw[j], acc[1][j]);
            }
        }
    }
    float4 b2v4 = *(const float4*)(b2 + tx * 4);
    float b2v[4] = {b2v4.x, b2v4.y, b2v4.z, b2v4.w};
#pragma unroll
    for (int i = 0; i < 2; ++i) {
        float e[4];
#pragma unroll
        for (int j = 0; j < 4; ++j) e[j] = acc[i][j] + b2v[j];
        float ss = e[0] * e[0] + e[1] * e[1] + e[2] * e[2] + e[3] * e[3];
        ss += __shfl_xor(ss, 8, 64);
        ss += __shfl_xor(ss, 4, 64);
        ss += __shfl_xor(ss, 2, 64);
        ss += __shfl_xor(ss, 1, 64);
        float nrm = fmaxf(sqrtf(ss), 1e-12f);
        float o[4];
#pragma unroll
        for (int j = 0; j < 4; ++j) o[j] = e[j] / nrm;
        *(float4*)(Ze + (size_t)(row0 + ty * 2 + i) * DCODEX + tx * 4) = *(float4*)&o[0];
    }
}

// ---------------------------------------------------------------------------
__device__ __forceinline__ unsigned fenc(float f) {
    unsigned u = __float_as_uint(f);
    return (u & 0x80000000u) ? ~u : (u | 0x80000000u);
}
__device__ __forceinline__ unsigned long long ullmin2(unsigned long long a,
                                                      unsigned long long b) {
    return a < b ? a : b;
}

// dist = cn2[k] - 2 z.c via bf16x6 MFMA; argmin via u64 keys.
// 128 tokens x 128 codes per block, grid (64, 64), K=64 in 2 tiles of 32.
__global__ __launch_bounds__(256) void dist_mfma_kernel(const unsigned short* __restrict__ Zh,
                                                        const unsigned short* __restrict__ Zm,
                                                        const unsigned short* __restrict__ Zl,
                                                        const unsigned short* __restrict__ Ch,
                                                        const unsigned short* __restrict__ Cm,
                                                        const unsigned short* __restrict__ Cl,
                                                        const float* __restrict__ cn2,
                                                        unsigned long long* __restrict__ gbest) {
    __shared__ unsigned short Ash[3][128][36];   // tokens
    __shared__ unsigned short Bsh[3][128][36];   // codes
    __shared__ unsigned long long red[128];
    const int tid = threadIdx.x;
    const int row0 = blockIdx.x * 128;
    const int col0 = blockIdx.y * 128;
    const int wave = tid >> 6;
    const int lane = tid & 63;
    const int lrow = lane & 31;
    const int lhalf = lane >> 5;
    const int wm = wave >> 1, wn = wave & 1;

    const unsigned short* Ap[3] = {Zh, Zm, Zl};
    const unsigned short* Bp[3] = {Ch, Cm, Cl};

    if (tid < 128) red[tid] = 0xFFFFFFFFFFFFFFFFull;

    f32x16 acc[2][2];
#pragma unroll
    for (int i = 0; i < 2; ++i)
#pragma unroll
        for (int j = 0; j < 2; ++j)
#pragma unroll
            for (int r = 0; r < 16; ++r) acc[i][j][r] = 0.f;

#pragma unroll
    for (int k0 = 0; k0 < DCODEX; k0 += 32) {
        __syncthreads();
#pragma unroll
        for (int l = 0; l < 3; ++l) {
#pragma unroll
            for (int t = 0; t < 2; ++t) {
                int q = tid + t * 256;
                int r = q >> 2, kq = (q & 3) * 8;
                uint4 va = *(const uint4*)(Ap[l] + (size_t)(row0 + r) * DCODEX + k0 + kq);
                *(uint2*)&Ash[l][r][kq]     = make_uint2(va.x, va.y);
                *(uint2*)&Ash[l][r][kq + 4] = make_uint2(va.z, va.w);
                uint4 vb = *(const uint4*)(Bp[l] + (size_t)(col0 + r) * DCODEX + k0 + kq);
                *(uint2*)&Bsh[l][r][kq]     = make_uint2(vb.x, vb.y);
                *(uint2*)&Bsh[l][r][kq + 4] = make_uint2(vb.z, vb.w);
            }
        }
        __syncthreads();
#pragma unroll
        for (int mk = 0; mk < 2; ++mk) {
            const int kb = mk * 16 + lhalf * 8;
            Frag ah[2], am[2], al[2], bh[2], bm[2], bl[2];
#pragma unroll
            for (int ti = 0; ti < 2; ++ti) {
                int rA = wm * 64 + ti * 32 + lrow;
                ah[ti].u[0] = *(const uint2*)&Ash[0][rA][kb];
                ah[ti].u[1] = *(const uint2*)&Ash[0][rA][kb + 4];
                am[ti].u[0] = *(const uint2*)&Ash[1][rA][kb];
                am[ti].u[1] = *(const uint2*)&Ash[1][rA][kb + 4];
                al[ti].u[0] = *(const uint2*)&Ash[2][rA][kb];
                al[ti].u[1] = *(const uint2*)&Ash[2][rA][kb + 4];
            }
#pragma unroll
            for (int tj = 0; tj < 2; ++tj) {
                int rB = wn * 64 + tj * 32 + lrow;
                bh[tj].u[0] = *(const uint2*)&Bsh[0][rB][kb];
                bh[tj].u[1] = *(const uint2*)&Bsh[0][rB][kb + 4];
                bm[tj].u[0] = *(const uint2*)&Bsh[1][rB][kb];
                bm[tj].u[1] = *(const uint2*)&Bsh[1][rB][kb + 4];
                bl[tj].u[0] = *(const uint2*)&Bsh[2][rB][kb];
                bl[tj].u[1] = *(const uint2*)&Bsh[2][rB][kb + 4];
            }
#pragma unroll
            for (int ti = 0; ti < 2; ++ti)
#pragma unroll
                for (int tj = 0; tj < 2; ++tj) {
                    acc[ti][tj] = __builtin_amdgcn_mfma_f32_32x32x16_bf16(ah[ti].s, bh[tj].s, acc[ti][tj], 0, 0, 0);
                    acc[ti][tj] = __builtin_amdgcn_mfma_f32_32x32x16_bf16(ah[ti].s, bm[tj].s, acc[ti][tj], 0, 0, 0);
                    acc[ti][tj] = __builtin_amdgcn_mfma_f32_32x32x16_bf16(am[ti].s, bh[tj].s, acc[ti][tj], 0, 0, 0);
                    acc[ti][tj] = __builtin_amdgcn_mfma_f32_32x32x16_bf16(am[ti].s, bm[tj].s, acc[ti][tj], 0, 0, 0);
                    acc[ti][tj] = __builtin_amdgcn_mfma_f32_32x32x16_bf16(ah[ti].s, bl[tj].s, acc[ti][tj], 0, 0, 0);
                    acc[ti][tj] = __builtin_amdgcn_mfma_f32_32x32x16_bf16(al[ti].s, bh[tj].s, acc[ti][tj], 0, 0, 0);
                }
        }
    }

    // epilogue: dist = cn - 2s; per-row u64 key min over 32 lanes of each half
    float cnv[2];
#pragma unroll
    for (int tj = 0; tj < 2; ++tj) cnv[tj] = cn2[col0 + wn * 64 + tj * 32 + lrow];
#pragma unroll
    for (int ti = 0; ti < 2; ++ti) {
#pragma unroll
        for (int r = 0; r < 16; ++r) {
            int rloc = wm * 64 + ti * 32 + (r & 3) + 8 * (r >> 2) + 4 * lhalf;
            unsigned long long kmin = 0xFFFFFFFFFFFFFFFFull;
#pragma unroll
            for (int tj = 0; tj < 2; ++tj) {
                float dist = fmaf(-2.0f, acc[ti][tj][r], cnv[tj]);
                unsigned col = (unsigned)(col0 + wn * 64 + tj * 32 + lrow);
                unsigned long long key = ((unsigned long long)fenc(dist) << 32) | col;
                kmin = ullmin2(kmin, key);
            }
#pragma unroll
            for (int m = 1; m <= 16; m <<= 1)
                kmin = ullmin2(kmin, (unsigned long long)__shfl_xor((long long)kmin, m, 64));
            if (lrow == 0) atomicMin(&red[rloc], kmin);
        }
    }
    __syncthreads();
    if (tid < 128) atomicMin(&gbest[row0 + tid], red[tid]);
}

// ---------------------------------------------------------------------------
// probs = one_hot(argmin) : fused zero-fill + scatter (268 MB single pass)
__global__ __launch_bounds__(256) void zero_scatter_kernel(const unsigned long long* __restrict__ gbest,
                                                           float* __restrict__ probs) {
    size_t g = (size_t)blockIdx.x * 256 + threadIdx.x;
    int row = (int)(g >> 11);
    int c4i = (int)(g & 2047);
    unsigned id = (unsigned)(gbest[row] & 0xFFFFFFFFull);
    float4 v = {0.f, 0.f, 0.f, 0.f};
    if ((id >> 2) == (unsigned)c4i) ((float*)&v)[id & 3] = 1.0f;
    *(float4*)(probs + ((size_t)row << 13) + ((size_t)c4i << 2)) = v;
}

// ---------------------------------------------------------------------------
// STE + LayerNorm + commitment loss; writes normalized rows to Aln
__global__ __launch_bounds__(256) void ln_loss_kernel(const unsigned long long* __restrict__ gbest,
                                                      const float* __restrict__ codex,
                                                      const float* __restrict__ Ze,
                                                      const float* __restrict__ ln_w,
                                                      const float* __restrict__ ln_b,
                                                      float* __restrict__ Aln,
                                                      float* __restrict__ loss) {
    const int tid = threadIdx.x;
    const int w = tid >> 6, l = tid & 63;
    const int row = blockIdx.x * 4 + w;
    int id = (int)(unsigned)(gbest[row] & 0xFFFFFFFFull);
    float zq = codex[(size_t)id * DCODEX + l];
    float ze = Ze[(size_t)row * DCODEX + l];
    float dlt = zq - ze;
    float val = ze + dlt;   // STE forward value (reference rounding)
    float s = val;
#pragma unroll
    for (int m = 32; m >= 1; m >>= 1) s += __shfl_xor(s, m, 64);
    float mu = s * 0.015625f;
    float c = val - mu;
    float v2 = c * c;
#pragma unroll
    for (int m = 32; m >= 1; m >>= 1) v2 += __shfl_xor(v2, m, 64);
    float var = v2 * 0.015625f;
    float y = c * (1.0f / sqrtf(var + 1e-5f)) * ln_w[l] + ln_b[l];
    Aln[(size_t)row * DCODEX + l] = y;
    float d2 = dlt * dlt;
#pragma unroll
    for (int m = 32; m >= 1; m >>= 1) d2 += __shfl_xor(d2, m, 64);
    if (l == 0) atomicAdd(loss, d2 * (1.0f / 524288.0f));  // BETA=1, /(N*64)
}

// ---------------------------------------------------------------------------
// Zq = Aln @ Wp + bp : 128x64 tile, grid (64,16), 8x4/thread, K=64 one-shot
__global__ __launch_bounds__(256) void gemm3_kernel(const float* __restrict__ Aln,
                                                    const float* __restrict__ Wp,
                                                    const float* __restrict__ bp,
                                                    float* __restrict__ Zq) {
    __shared__ float As[64][132];   // As[d][token]
    __shared__ float Bs[64][68];    // Bs[d][col]
    const int tid = threadIdx.x;
    const int row0 = blockIdx.x * 128;
    const int col0 = blockIdx.y * 64;
    const int ty = tid >> 4, tx = tid & 15;

#pragma unroll
    for (int t = 0; t < 8; ++t) {
        int q = tid + t * 256;
        int r = q >> 4, d4 = (q & 15) * 4;
        float4 v = *(const float4*)(Aln + (size_t)(row0 + r) * DCODEX + d4);
        As[d4 + 0][r] = v.x; As[d4 + 1][r] = v.y;
        As[d4 + 2][r] = v.z; As[d4 + 3][r] = v.w;
    }
#pragma unroll
    for (int t = 0; t < 4; ++t) {
        int q = tid + t * 256;
        int kk = q >> 4, c4 = (q & 15) * 4;
        *(float4*)&Bs[kk][c4] = *(const float4*)(Wp + (size_t)kk * DMODEL + col0 + c4);
    }
    __syncthreads();

    float acc[8][4];
#pragma unroll
    for (int i = 0; i < 8; ++i)
#pragma unroll
        for (int j = 0; j < 4; ++j) acc[i][j] = 0.f;
#pragma unroll
    for (int k = 0; k < 64; ++k) {
        float a[8];
        *(float4*)&a[0] = *(const float4*)&As[k][ty * 4];
        *(float4*)&a[4] = *(const float4*)&As[k][64 + ty * 4];
        float4 b = *(const float4*)&Bs[k][tx * 4];
        float bw[4] = {b.x, b.y, b.z, b.w};
#pragma unroll
        for (int i = 0; i < 8; ++i)
#pragma unroll
            for (int j = 0; j < 4; ++j)
                acc[i][j] = fmaf(a[i], bw[j], acc[i][j]);
    }
    float4 bp4 = *(const float4*)(bp + col0 + tx * 4);
    float bb[4] = {bp4.x, bp4.y, bp4.z, bp4.w};
#pragma unroll
    for (int half = 0; half < 2; ++half)
#pragma unroll
        for (int i = 0; i < 4; ++i) {
            int r = row0 + half * 64 + ty * 4 + i;
            float o[4];
#pragma unroll
            for (int j = 0; j < 4; ++j) o[j] = acc[half * 4 + i][j] + bb[j];
            *(float4*)(Zq + (size_t)r * DMODEL + col0 + tx * 4) = *(float4*)&o[0];
        }
}

// ---------------------------------------------------------------------------
extern "C" void kernel_launch(void* const* d_in, const int* in_sizes, int n_in,
                              void* d_out, int out_size, void* d_ws, size_t ws_size,
                              hipStream_t stream) {
    const float* Z     = (const float*)d_in[0];
    const float* W1    = (const float*)d_in[1];
    const float* b1    = (const float*)d_in[2];
    const float* W2    = (const float*)d_in[3];
    const float* b2    = (const float*)d_in[4];
    const float* codex = (const float*)d_in[5];
    const float* ln_w  = (const float*)d_in[6];
    const float* ln_b  = (const float*)d_in[7];
    const float* Wp    = (const float*)d_in[8];
    const float* bp    = (const float*)d_in[9];

    float* out      = (float*)d_out;
    float* Zq_out   = out;                          // 8192*1024
    float* loss_out = out + (size_t)N_TOK * DMODEL; // 1
    float* probs    = loss_out + 1;                 // 8192*8192

    // workspace layout (~103 MB)
    char* ws = (char*)d_ws;
    float* H   = (float*)ws;                                   // 8192*1024 fp32
    float* Aln = H;                                            // 8192*64 (alias, H dead)
    float* Ze  = H + (size_t)N_TOK * DMODEL;                   // 8192*64
    float* cn2 = Ze + (size_t)N_TOK * DCODEX;                  // 8192
    unsigned long long* gbest = (unsigned long long*)(cn2 + KCODES);   // 8192
    unsigned short* W1t0 = (unsigned short*)(gbest + N_TOK);   // 3 x 1024*1024 bf16
    unsigned short* W1t1 = W1t0 + (size_t)DMODEL * DMODEL;
    unsigned short* W1t2 = W1t1 + (size_t)DMODEL * DMODEL;
    unsigned short* Zt0  = W1t2 + (size_t)DMODEL * DMODEL;     // 3 x 8192*1024 bf16
    unsigned short* Zt1  = Zt0 + (size_t)N_TOK * DMODEL;
    unsigned short* Zt2  = Zt1 + (size_t)N_TOK * DMODEL;
    unsigned short* Zeh  = Zt2 + (size_t)N_TOK * DMODEL;       // 3 x 8192*64 bf16
    unsigned short* Zem  = Zeh + (size_t)N_TOK * DCODEX;
    unsigned short* Zel  = Zem + (size_t)N_TOK * DCODEX;
    unsigned short* Chh  = Zel + (size_t)N_TOK * DCODEX;       // 3 x 8192*64 bf16
    unsigned short* Chm  = Chh + (size_t)KCODES * DCODEX;
    unsigned short* Chl  = Chm + (size_t)KCODES * DCODEX;

    hipMemsetAsync(loss_out, 0, sizeof(float), stream);
    hipMemsetAsync(gbest, 0xFF, (size_t)N_TOK * sizeof(unsigned long long), stream);

    codenorm_kernel<<<KCODES / 256, 256, 0, stream>>>(codex, cn2);
    split_w1_kernel<<<dim3(DMODEL / 32, DMODEL / 32), 256, 0, stream>>>(W1, W1t0, W1t1, W1t2);
    split3_kernel<<<(int)(((size_t)N_TOK * DMODEL) / 1024), 256, 0, stream>>>(Z, Zt0, Zt1, Zt2);
    split3_kernel<<<(int)(((size_t)KCODES * DCODEX) / 1024), 256, 0, stream>>>(codex, Chh, Chm, Chl);
    gemm1_mfma_kernel<<<dim3(N_TOK / 128, DMODEL / 128), 256, 0, stream>>>(Zt0, Zt1, Zt2, W1t0, W1t1, W1t2, b1, H);
    gemm2_norm_kernel<<<N_TOK / 32, 256, 0, stream>>>(H, W2, b2, Ze);
    split3_kernel<<<(int)(((size_t)N_TOK * DCODEX) / 1024), 256, 0, stream>>>(Ze, Zeh, Zem, Zel);
    dist_mfma_kernel<<<dim3(N_TOK / 128, KCODES / 128), 256, 0, stream>>>(Zeh, Zem, Zel, Chh, Chm, Chl, cn2, gbest);
    zero_scatter_kernel<<<(int)(((size_t)N_TOK * KCODES / 4) / 256), 256, 0, stream>>>(gbest, probs);
    ln_loss_kernel<<<N_TOK / 4, 256, 0, stream>>>(gbest, codex, Ze, ln_w, ln_b, Aln, loss_out);
    gemm3_kernel<<<dim3(N_TOK / 128, DMODEL / 64), 256, 0, stream>>>(Aln, Wp, bp, Zq_out);
}

// Round 7
// 731.374 us; speedup vs baseline: 1.0575x; 1.0575x over previous
//
#include <hip/hip_runtime.h>
#include <math.h>
#include <stdint.h>

#define N_TOK   8192      // B*S = 4*2048
#define DMODEL  1024
#define DCODEX  64
#define KCODES  8192

typedef short short8 __attribute__((ext_vector_type(8)));
typedef _Float16 half8 __attribute__((ext_vector_type(8)));
typedef float f32x16 __attribute__((ext_vector_type(16)));
typedef float f32x4  __attribute__((ext_vector_type(4)));

union Frag  { short8 s; uint2 u[2]; };
union FragH { half8  h; uint2 u[2]; };
union H16   { _Float16 h; unsigned short s; };

// fp32 -> bf16 RNE, and back
__device__ __forceinline__ unsigned short f2bf(float f) {
    unsigned u = __float_as_uint(f);
    unsigned r = u + 0x7FFFu + ((u >> 16) & 1u);
    return (unsigned short)(r >> 16);
}
__device__ __forceinline__ float bf2f(unsigned short h) {
    return __uint_as_float(((unsigned)h) << 16);
}

// ---------------------------------------------------------------------------
// cn2[k] = sum_d codex[k][d]^2
__global__ __launch_bounds__(256) void codenorm_kernel(const float* __restrict__ codex,
                                                       float* __restrict__ cn2) {
    int k = blockIdx.x * 256 + threadIdx.x;
    const float4* p = (const float4*)(codex + (size_t)k * DCODEX);
    float s = 0.f;
#pragma unroll
    for (int i = 0; i < 16; ++i) {
        float4 v = p[i];
        s += v.x * v.x + v.y * v.y + v.z * v.z + v.w * v.w;
    }
    cn2[k] = s;
}

// ---------------------------------------------------------------------------
// Flat 3-way bf16 split (hi/mid/lo), row-major preserved. 4 floats/thread.
__global__ __launch_bounds__(256) void split3_kernel(const float* __restrict__ src,
                                                     unsigned short* __restrict__ p0,
                                                     unsigned short* __restrict__ p1,
                                                     unsigned short* __restrict__ p2) {
    size_t i4 = ((size_t)blockIdx.x * 256 + threadIdx.x) * 4;
    float4 v = *(const float4*)(src + i4);
    float f[4] = {v.x, v.y, v.z, v.w};
    ushort4 h0, h1, h2;
#pragma unroll
    for (int c = 0; c < 4; ++c) {
        unsigned short a0 = f2bf(f[c]);
        float r1 = f[c] - bf2f(a0);
        unsigned short a1 = f2bf(r1);
        float r2 = r1 - bf2f(a1);
        unsigned short a2 = f2bf(r2);
        ((unsigned short*)&h0)[c] = a0;
        ((unsigned short*)&h1)[c] = a1;
        ((unsigned short*)&h2)[c] = a2;
    }
    *(ushort4*)(p0 + i4) = h0;
    *(ushort4*)(p1 + i4) = h1;
    *(ushort4*)(p2 + i4) = h2;
}

// ---------------------------------------------------------------------------
// Flat 2-way fp16 split (hi/residual). 4 floats/thread.
__global__ __launch_bounds__(256) void split2h_kernel(const float* __restrict__ src,
                                                      unsigned short* __restrict__ p0,
                                                      unsigned short* __restrict__ p1) {
    size_t i4 = ((size_t)blockIdx.x * 256 + threadIdx.x) * 4;
    float4 v = *(const float4*)(src + i4);
    float f[4] = {v.x, v.y, v.z, v.w};
    ushort4 h0, h1;
#pragma unroll
    for (int c = 0; c < 4; ++c) {
        H16 a0, a1;
        a0.h = (_Float16)f[c];
        float r = f[c] - (float)a0.h;
        a1.h = (_Float16)r;
        ((unsigned short*)&h0)[c] = a0.s;
        ((unsigned short*)&h1)[c] = a1.s;
    }
    *(ushort4*)(p0 + i4) = h0;
    *(ushort4*)(p1 + i4) = h1;
}

// ---------------------------------------------------------------------------
// Split W1 (k x n, fp32) into 3 transposed bf16 planes W1t_l[n][k].
__global__ __launch_bounds__(256) void split_w1_kernel(const float* __restrict__ W1,
                                                       unsigned short* __restrict__ t0,
                                                       unsigned short* __restrict__ t1,
                                                       unsigned short* __restrict__ t2) {
    __shared__ float tile[32][33];
    const int tid = threadIdx.x;
    const int k0 = blockIdx.x * 32;
    const int n0 = blockIdx.y * 32;
    {
        int i = tid >> 3, j4 = (tid & 7) * 4;
        float4 v = *(const float4*)(W1 + (size_t)(k0 + i) * DMODEL + n0 + j4);
        tile[i][j4 + 0] = v.x; tile[i][j4 + 1] = v.y;
        tile[i][j4 + 2] = v.z; tile[i][j4 + 3] = v.w;
    }
    __syncthreads();
    int n = tid >> 3, kq = (tid & 7) * 4;
    ushort4 h0, h1, h2;
#pragma unroll
    for (int c = 0; c < 4; ++c) {
        float f = tile[kq + c][n];
        unsigned short a0 = f2bf(f);
        float r1 = f - bf2f(a0);
        unsigned short a1 = f2bf(r1);
        float r2 = r1 - bf2f(a1);
        unsigned short a2 = f2bf(r2);
        ((unsigned short*)&h0)[c] = a0;
        ((unsigned short*)&h1)[c] = a1;
        ((unsigned short*)&h2)[c] = a2;
    }
    size_t off = (size_t)(n0 + n) * DMODEL + k0 + kq;
    *(ushort4*)(t0 + off) = h0;
    *(ushort4*)(t1 + off) = h1;
    *(ushort4*)(t2 + off) = h2;
}

// ---------------------------------------------------------------------------
// H = tanh(Z @ W1 + b1) via bf16x6 MFMA; A and B both pre-split bf16 planes.
// 128x128 block tile, 4 waves 2x2, 64x64/wave (2x2 of 32x32x16).
__global__ __launch_bounds__(256) void gemm1_mfma_kernel(const unsigned short* __restrict__ Zt0,
                                                         const unsigned short* __restrict__ Zt1,
                                                         const unsigned short* __restrict__ Zt2,
                                                         const unsigned short* __restrict__ W1t0,
                                                         const unsigned short* __restrict__ W1t1,
                                                         const unsigned short* __restrict__ W1t2,
                                                         const float* __restrict__ b1,
                                                         float* __restrict__ H) {
    __shared__ unsigned short Ash[3][128][36];   // [level][m][k] pitch 36
    __shared__ unsigned short Bsh[3][128][36];   // [level][n][k] pitch 36
    const int tid = threadIdx.x;
    const int row0 = blockIdx.x * 128;
    const int col0 = blockIdx.y * 128;
    const int wave = tid >> 6;
    const int lane = tid & 63;
    const int lrow = lane & 31;
    const int lhalf = lane >> 5;
    const int wm = wave >> 1, wn = wave & 1;

    const unsigned short* Ap[3] = {Zt0, Zt1, Zt2};
    const unsigned short* Bp[3] = {W1t0, W1t1, W1t2};

    f32x16 acc[2][2];
#pragma unroll
    for (int i = 0; i < 2; ++i)
#pragma unroll
        for (int j = 0; j < 2; ++j)
#pragma unroll
            for (int r = 0; r < 16; ++r) acc[i][j][r] = 0.f;

    for (int k0 = 0; k0 < DMODEL; k0 += 32) {
        __syncthreads();   // WAR on Ash/Bsh
#pragma unroll
        for (int l = 0; l < 3; ++l) {
#pragma unroll
            for (int t = 0; t < 2; ++t) {
                int q = tid + t * 256;
                int r = q >> 2, kq = (q & 3) * 8;
                uint4 va = *(const uint4*)(Ap[l] + (size_t)(row0 + r) * DMODEL + k0 + kq);
                *(uint2*)&Ash[l][r][kq]     = make_uint2(va.x, va.y);
                *(uint2*)&Ash[l][r][kq + 4] = make_uint2(va.z, va.w);
                uint4 vb = *(const uint4*)(Bp[l] + (size_t)(col0 + r) * DMODEL + k0 + kq);
                *(uint2*)&Bsh[l][r][kq]     = make_uint2(vb.x, vb.y);
                *(uint2*)&Bsh[l][r][kq + 4] = make_uint2(vb.z, vb.w);
            }
        }
        __syncthreads();
#pragma unroll
        for (int mk = 0; mk < 2; ++mk) {
            const int kb = mk * 16 + lhalf * 8;
            Frag ah[2], am[2], al[2], bh[2], bm[2], bl[2];
#pragma unroll
            for (int ti = 0; ti < 2; ++ti) {
                int rA = wm * 64 + ti * 32 + lrow;
                ah[ti].u[0] = *(const uint2*)&Ash[0][rA][kb];
                ah[ti].u[1] = *(const uint2*)&Ash[0][rA][kb + 4];
                am[ti].u[0] = *(const uint2*)&Ash[1][rA][kb];
                am[ti].u[1] = *(const uint2*)&Ash[1][rA][kb + 4];
                al[ti].u[0] = *(const uint2*)&Ash[2][rA][kb];
                al[ti].u[1] = *(const uint2*)&Ash[2][rA][kb + 4];
            }
#pragma unroll
            for (int tj = 0; tj < 2; ++tj) {
                int rB = wn * 64 + tj * 32 + lrow;
                bh[tj].u[0] = *(const uint2*)&Bsh[0][rB][kb];
                bh[tj].u[1] = *(const uint2*)&Bsh[0][rB][kb + 4];
                bm[tj].u[0] = *(const uint2*)&Bsh[1][rB][kb];
                bm[tj].u[1] = *(const uint2*)&Bsh[1][rB][kb + 4];
                bl[tj].u[0] = *(const uint2*)&Bsh[2][rB][kb];
                bl[tj].u[1] = *(const uint2*)&Bsh[2][rB][kb + 4];
            }
#pragma unroll
            for (int ti = 0; ti < 2; ++ti)
#pragma unroll
                for (int tj = 0; tj < 2; ++tj) {
                    acc[ti][tj] = __builtin_amdgcn_mfma_f32_32x32x16_bf16(ah[ti].s, bh[tj].s, acc[ti][tj], 0, 0, 0);
                    acc[ti][tj] = __builtin_amdgcn_mfma_f32_32x32x16_bf16(ah[ti].s, bm[tj].s, acc[ti][tj], 0, 0, 0);
                    acc[ti][tj] = __builtin_amdgcn_mfma_f32_32x32x16_bf16(am[ti].s, bh[tj].s, acc[ti][tj], 0, 0, 0);
                    acc[ti][tj] = __builtin_amdgcn_mfma_f32_32x32x16_bf16(am[ti].s, bm[tj].s, acc[ti][tj], 0, 0, 0);
                    acc[ti][tj] = __builtin_amdgcn_mfma_f32_32x32x16_bf16(ah[ti].s, bl[tj].s, acc[ti][tj], 0, 0, 0);
                    acc[ti][tj] = __builtin_amdgcn_mfma_f32_32x32x16_bf16(al[ti].s, bh[tj].s, acc[ti][tj], 0, 0, 0);
                }
        }
    }

    float b1v[2];
#pragma unroll
    for (int tj = 0; tj < 2; ++tj) b1v[tj] = b1[col0 + wn * 64 + tj * 32 + lrow];
#pragma unroll
    for (int ti = 0; ti < 2; ++ti)
#pragma unroll
        for (int tj = 0; tj < 2; ++tj) {
            int col = col0 + wn * 64 + tj * 32 + lrow;
#pragma unroll
            for (int r = 0; r < 16; ++r) {
                int row = row0 + wm * 64 + ti * 32 + (r & 3) + 8 * (r >> 2) + 4 * lhalf;
                H[(size_t)row * DMODEL + col] = tanhf(acc[ti][tj][r] + b1v[tj]);
            }
        }
}

// ---------------------------------------------------------------------------
// E = H @ W2 + b2 ; Ze = E / max(||E||_row, 1e-12)
__global__ __launch_bounds__(256) void gemm2_norm_kernel(const float* __restrict__ H,
                                                         const float* __restrict__ W2,
                                                         const float* __restrict__ b2,
                                                         float* __restrict__ Ze) {
    __shared__ float As[64][36];   // As[k][m] transposed
    __shared__ float Bs[64][68];   // Bs[k][n]
    const int tid = threadIdx.x;
    const int row0 = blockIdx.x * 32;
    const int ty = tid >> 4, tx = tid & 15;

    float acc[2][4];
#pragma unroll
    for (int i = 0; i < 2; ++i)
#pragma unroll
        for (int j = 0; j < 4; ++j) acc[i][j] = 0.f;

    for (int k0 = 0; k0 < DMODEL; k0 += 64) {
        __syncthreads();   // WAR
#pragma unroll
        for (int t = 0; t < 2; ++t) {
            int q = tid + t * 256;
            int r = q >> 4, k4 = (q & 15) * 4;
            float4 v = *(const float4*)(H + (size_t)(row0 + r) * DMODEL + k0 + k4);
            As[k4 + 0][r] = v.x; As[k4 + 1][r] = v.y;
            As[k4 + 2][r] = v.z; As[k4 + 3][r] = v.w;
        }
#pragma unroll
        for (int t = 0; t < 4; ++t) {
            int q = tid + t * 256;
            int kk = q >> 4, c4 = (q & 15) * 4;
            *(float4*)&Bs[kk][c4] = *(const float4*)(W2 + (size_t)(k0 + kk) * DCODEX + c4);
        }
        __syncthreads();
#pragma unroll
        for (int k = 0; k < 64; ++k) {
            float2 a = *(const float2*)&As[k][ty * 2];
            float4 b = *(const float4*)&Bs[k][tx * 4];
            float bw[4] = {b.x, b.y, b.z, b.w};
#pragma unroll
            for (int j = 0; j < 4; ++j) {
                acc[0][j] = fmaf(a.x, bw[j], acc[0][j]);
                acc[1][j] = fmaf(a.y, bw[j], acc[1][j]);
            }
        }
    }
    float4 b2v4 = *(const float4*)(b2 + tx * 4);
    float b2v[4] = {b2v4.x, b2v4.y, b2v4.z, b2v4.w};
#pragma unroll
    for (int i = 0; i < 2; ++i) {
        float e[4];
#pragma unroll
        for (int j = 0; j < 4; ++j) e[j] = acc[i][j] + b2v[j];
        float ss = e[0] * e[0] + e[1] * e[1] + e[2] * e[2] + e[3] * e[3];
        ss += __shfl_xor(ss, 8, 64);
        ss += __shfl_xor(ss, 4, 64);
        ss += __shfl_xor(ss, 2, 64);
        ss += __shfl_xor(ss, 1, 64);
        float nrm = fmaxf(sqrtf(ss), 1e-12f);
        float o[4];
#pragma unroll
        for (int j = 0; j < 4; ++j) o[j] = e[j] / nrm;
        *(float4*)(Ze + (size_t)(row0 + ty * 2 + i) * DCODEX + tx * 4) = *(float4*)&o[0];
    }
}

// ---------------------------------------------------------------------------
__device__ __forceinline__ unsigned fenc(float f) {
    unsigned u = __float_as_uint(f);
    return (u & 0x80000000u) ? ~u : (u | 0x80000000u);
}
__device__ __forceinline__ unsigned long long ullmin2(unsigned long long a,
                                                      unsigned long long b) {
    return a < b ? a : b;
}

// dist = cn2[k] - 2 z.c via fp16-x3 MFMA (hh+hm+mh, fp32-fidelity to ~2^-22).
// 128 tokens x 128 codes per block, grid (64,64); K=64 staged ONCE (no k-loop).
__global__ __launch_bounds__(256) void dist_mfma_kernel(const unsigned short* __restrict__ Zh,
                                                        const unsigned short* __restrict__ Zm,
                                                        const unsigned short* __restrict__ Ch,
                                                        const unsigned short* __restrict__ Cm,
                                                        const float* __restrict__ cn2,
                                                        unsigned long long* __restrict__ gbest) {
    __shared__ unsigned short Ash[2][128][68];   // [level][token][k] pitch 68
    __shared__ unsigned short Bsh[2][128][68];   // [level][code][k]
    __shared__ unsigned long long red[128];
    const int tid = threadIdx.x;
    const int row0 = blockIdx.x * 128;
    const int col0 = blockIdx.y * 128;
    const int wave = tid >> 6;
    const int lane = tid & 63;
    const int lrow = lane & 31;
    const int lhalf = lane >> 5;
    const int wm = wave >> 1, wn = wave & 1;

    const unsigned short* Ap[2] = {Zh, Zm};
    const unsigned short* Bp[2] = {Ch, Cm};

    if (tid < 128) red[tid] = 0xFFFFFFFFFFFFFFFFull;

    // stage whole K=64: per level 1024 uint4 (A) + 1024 (B); 4+4 per thread
#pragma unroll
    for (int l = 0; l < 2; ++l) {
#pragma unroll
        for (int t = 0; t < 4; ++t) {
            int q = tid + t * 256;
            int r = q >> 3, kq = (q & 7) * 8;
            uint4 va = *(const uint4*)(Ap[l] + (size_t)(row0 + r) * DCODEX + kq);
            *(uint2*)&Ash[l][r][kq]     = make_uint2(va.x, va.y);
            *(uint2*)&Ash[l][r][kq + 4] = make_uint2(va.z, va.w);
            uint4 vb = *(const uint4*)(Bp[l] + (size_t)(col0 + r) * DCODEX + kq);
            *(uint2*)&Bsh[l][r][kq]     = make_uint2(vb.x, vb.y);
            *(uint2*)&Bsh[l][r][kq + 4] = make_uint2(vb.z, vb.w);
        }
    }
    __syncthreads();

    f32x16 acc[2][2];
#pragma unroll
    for (int i = 0; i < 2; ++i)
#pragma unroll
        for (int j = 0; j < 2; ++j)
#pragma unroll
            for (int r = 0; r < 16; ++r) acc[i][j][r] = 0.f;

#pragma unroll
    for (int mk = 0; mk < 4; ++mk) {
        const int kb = mk * 16 + lhalf * 8;
        FragH a0[2], a1[2], b0[2], b1[2];
#pragma unroll
        for (int ti = 0; ti < 2; ++ti) {
            int rA = wm * 64 + ti * 32 + lrow;
            a0[ti].u[0] = *(const uint2*)&Ash[0][rA][kb];
            a0[ti].u[1] = *(const uint2*)&Ash[0][rA][kb + 4];
            a1[ti].u[0] = *(const uint2*)&Ash[1][rA][kb];
            a1[ti].u[1] = *(const uint2*)&Ash[1][rA][kb + 4];
        }
#pragma unroll
        for (int tj = 0; tj < 2; ++tj) {
            int rB = wn * 64 + tj * 32 + lrow;
            b0[tj].u[0] = *(const uint2*)&Bsh[0][rB][kb];
            b0[tj].u[1] = *(const uint2*)&Bsh[0][rB][kb + 4];
            b1[tj].u[0] = *(const uint2*)&Bsh[1][rB][kb];
            b1[tj].u[1] = *(const uint2*)&Bsh[1][rB][kb + 4];
        }
#pragma unroll
        for (int ti = 0; ti < 2; ++ti)
#pragma unroll
            for (int tj = 0; tj < 2; ++tj) {
                acc[ti][tj] = __builtin_amdgcn_mfma_f32_32x32x16_f16(a0[ti].h, b0[tj].h, acc[ti][tj], 0, 0, 0);
                acc[ti][tj] = __builtin_amdgcn_mfma_f32_32x32x16_f16(a0[ti].h, b1[tj].h, acc[ti][tj], 0, 0, 0);
                acc[ti][tj] = __builtin_amdgcn_mfma_f32_32x32x16_f16(a1[ti].h, b0[tj].h, acc[ti][tj], 0, 0, 0);
            }
    }

    // epilogue: dist = cn - 2s; per-row u64 key min over the 32-lane half
    float cnv[2];
#pragma unroll
    for (int tj = 0; tj < 2; ++tj) cnv[tj] = cn2[col0 + wn * 64 + tj * 32 + lrow];
#pragma unroll
    for (int ti = 0; ti < 2; ++ti) {
#pragma unroll
        for (int r = 0; r < 16; ++r) {
            int rloc = wm * 64 + ti * 32 + (r & 3) + 8 * (r >> 2) + 4 * lhalf;
            unsigned long long kmin = 0xFFFFFFFFFFFFFFFFull;
#pragma unroll
            for (int tj = 0; tj < 2; ++tj) {
                float dist = fmaf(-2.0f, acc[ti][tj][r], cnv[tj]);
                unsigned col = (unsigned)(col0 + wn * 64 + tj * 32 + lrow);
                unsigned long long key = ((unsigned long long)fenc(dist) << 32) | col;
                kmin = ullmin2(kmin, key);
            }
#pragma unroll
            for (int m = 1; m <= 16; m <<= 1)
                kmin = ullmin2(kmin, (unsigned long long)__shfl_xor((long long)kmin, m, 64));
            if (lrow == 0) atomicMin(&red[rloc], kmin);
        }
    }
    __syncthreads();
    if (tid < 128) atomicMin(&gbest[row0 + tid], red[tid]);
}

// ---------------------------------------------------------------------------
// probs = one_hot(argmin) : fused zero-fill + scatter, nontemporal (write-once)
__global__ __launch_bounds__(256) void zero_scatter_kernel(const unsigned long long* __restrict__ gbest,
                                                           float* __restrict__ probs) {
    size_t g = (size_t)blockIdx.x * 256 + threadIdx.x;
    int row = (int)(g >> 11);
    int c4i = (int)(g & 2047);
    unsigned id = (unsigned)(gbest[row] & 0xFFFFFFFFull);
    f32x4 v = {0.f, 0.f, 0.f, 0.f};
    if ((id >> 2) == (unsigned)c4i) v[id & 3] = 1.0f;
    __builtin_nontemporal_store(v, (f32x4*)(probs + ((size_t)row << 13) + ((size_t)c4i << 2)));
}

// ---------------------------------------------------------------------------
// STE + LayerNorm + commitment loss; writes normalized rows to Aln
__global__ __launch_bounds__(256) void ln_loss_kernel(const unsigned long long* __restrict__ gbest,
                                                      const float* __restrict__ codex,
                                                      const float* __restrict__ Ze,
                                                      const float* __restrict__ ln_w,
                                                      const float* __restrict__ ln_b,
                                                      float* __restrict__ Aln,
                                                      float* __restrict__ loss) {
    const int tid = threadIdx.x;
    const int w = tid >> 6, l = tid & 63;
    const int row = blockIdx.x * 4 + w;
    int id = (int)(unsigned)(gbest[row] & 0xFFFFFFFFull);
    float zq = codex[(size_t)id * DCODEX + l];
    float ze = Ze[(size_t)row * DCODEX + l];
    float dlt = zq - ze;
    float val = ze + dlt;   // STE forward value (reference rounding)
    float s = val;
#pragma unroll
    for (int m = 32; m >= 1; m >>= 1) s += __shfl_xor(s, m, 64);
    float mu = s * 0.015625f;
    float c = val - mu;
    float v2 = c * c;
#pragma unroll
    for (int m = 32; m >= 1; m >>= 1) v2 += __shfl_xor(v2, m, 64);
    float var = v2 * 0.015625f;
    float y = c * (1.0f / sqrtf(var + 1e-5f)) * ln_w[l] + ln_b[l];
    Aln[(size_t)row * DCODEX + l] = y;
    float d2 = dlt * dlt;
#pragma unroll
    for (int m = 32; m >= 1; m >>= 1) d2 += __shfl_xor(d2, m, 64);
    if (l == 0) atomicAdd(loss, d2 * (1.0f / 524288.0f));  // BETA=1, /(N*64)
}

// ---------------------------------------------------------------------------
// Zq = Aln @ Wp + bp : 128x64 tile, grid (64,16), 8x4/thread, K=64 one-shot
__global__ __launch_bounds__(256) void gemm3_kernel(const float* __restrict__ Aln,
                                                    const float* __restrict__ Wp,
                                                    const float* __restrict__ bp,
                                                    float* __restrict__ Zq) {
    __shared__ float As[64][132];   // As[d][token]
    __shared__ float Bs[64][68];    // Bs[d][col]
    const int tid = threadIdx.x;
    const int row0 = blockIdx.x * 128;
    const int col0 = blockIdx.y * 64;
    const int ty = tid >> 4, tx = tid & 15;

#pragma unroll
    for (int t = 0; t < 8; ++t) {
        int q = tid + t * 256;
        int r = q >> 4, d4 = (q & 15) * 4;
        float4 v = *(const float4*)(Aln + (size_t)(row0 + r) * DCODEX + d4);
        As[d4 + 0][r] = v.x; As[d4 + 1][r] = v.y;
        As[d4 + 2][r] = v.z; As[d4 + 3][r] = v.w;
    }
#pragma unroll
    for (int t = 0; t < 4; ++t) {
        int q = tid + t * 256;
        int kk = q >> 4, c4 = (q & 15) * 4;
        *(float4*)&Bs[kk][c4] = *(const float4*)(Wp + (size_t)kk * DMODEL + col0 + c4);
    }
    __syncthreads();

    float acc[8][4];
#pragma unroll
    for (int i = 0; i < 8; ++i)
#pragma unroll
        for (int j = 0; j < 4; ++j) acc[i][j] = 0.f;
#pragma unroll
    for (int k = 0; k < 64; ++k) {
        float a[8];
        *(float4*)&a[0] = *(const float4*)&As[k][ty * 4];
        *(float4*)&a[4] = *(const float4*)&As[k][64 + ty * 4];
        float4 b = *(const float4*)&Bs[k][tx * 4];
        float bw[4] = {b.x, b.y, b.z, b.w};
#pragma unroll
        for (int i = 0; i < 8; ++i)
#pragma unroll
            for (int j = 0; j < 4; ++j)
                acc[i][j] = fmaf(a[i], bw[j], acc[i][j]);
    }
    float4 bp4 = *(const float4*)(bp + col0 + tx * 4);
    float bb[4] = {bp4.x, bp4.y, bp4.z, bp4.w};
#pragma unroll
    for (int half = 0; half < 2; ++half)
#pragma unroll
        for (int i = 0; i < 4; ++i) {
            int r = row0 + half * 64 + ty * 4 + i;
            float o[4];
#pragma unroll
            for (int j = 0; j < 4; ++j) o[j] = acc[half * 4 + i][j] + bb[j];
            *(float4*)(Zq + (size_t)r * DMODEL + col0 + tx * 4) = *(float4*)&o[0];
        }
}

// ---------------------------------------------------------------------------
extern "C" void kernel_launch(void* const* d_in, const int* in_sizes, int n_in,
                              void* d_out, int out_size, void* d_ws, size_t ws_size,
                              hipStream_t stream) {
    const float* Z     = (const float*)d_in[0];
    const float* W1    = (const float*)d_in[1];
    const float* b1    = (const float*)d_in[2];
    const float* W2    = (const float*)d_in[3];
    const float* b2    = (const float*)d_in[4];
    const float* codex = (const float*)d_in[5];
    const float* ln_w  = (const float*)d_in[6];
    const float* ln_b  = (const float*)d_in[7];
    const float* Wp    = (const float*)d_in[8];
    const float* bp    = (const float*)d_in[9];

    float* out      = (float*)d_out;
    float* Zq_out   = out;                          // 8192*1024
    float* loss_out = out + (size_t)N_TOK * DMODEL; // 1
    float* probs    = loss_out + 1;                 // 8192*8192

    // workspace layout (~95 MB)
    char* ws = (char*)d_ws;
    float* H   = (float*)ws;                                   // 8192*1024 fp32
    float* Aln = H;                                            // 8192*64 (alias, H dead)
    float* Ze  = H + (size_t)N_TOK * DMODEL;                   // 8192*64
    float* cn2 = Ze + (size_t)N_TOK * DCODEX;                  // 8192
    unsigned long long* gbest = (unsigned long long*)(cn2 + KCODES);   // 8192
    unsigned short* W1t0 = (unsigned short*)(gbest + N_TOK);   // 3 x 1024*1024 bf16
    unsigned short* W1t1 = W1t0 + (size_t)DMODEL * DMODEL;
    unsigned short* W1t2 = W1t1 + (size_t)DMODEL * DMODEL;
    unsigned short* Zt0  = W1t2 + (size_t)DMODEL * DMODEL;     // 3 x 8192*1024 bf16
    unsigned short* Zt1  = Zt0 + (size_t)N_TOK * DMODEL;
    unsigned short* Zt2  = Zt1 + (size_t)N_TOK * DMODEL;
    unsigned short* Zeh  = Zt2 + (size_t)N_TOK * DMODEL;       // 2 x 8192*64 fp16
    unsigned short* Zem  = Zeh + (size_t)N_TOK * DCODEX;
    unsigned short* Cxh  = Zem + (size_t)N_TOK * DCODEX;       // 2 x 8192*64 fp16
    unsigned short* Cxm  = Cxh + (size_t)KCODES * DCODEX;

    hipMemsetAsync(loss_out, 0, sizeof(float), stream);
    hipMemsetAsync(gbest, 0xFF, (size_t)N_TOK * sizeof(unsigned long long), stream);

    codenorm_kernel<<<KCODES / 256, 256, 0, stream>>>(codex, cn2);
    split_w1_kernel<<<dim3(DMODEL / 32, DMODEL / 32), 256, 0, stream>>>(W1, W1t0, W1t1, W1t2);
    split3_kernel<<<(int)(((size_t)N_TOK * DMODEL) / 1024), 256, 0, stream>>>(Z, Zt0, Zt1, Zt2);
    split2h_kernel<<<(int)(((size_t)KCODES * DCODEX) / 1024), 256, 0, stream>>>(codex, Cxh, Cxm);
    gemm1_mfma_kernel<<<dim3(N_TOK / 128, DMODEL / 128), 256, 0, stream>>>(Zt0, Zt1, Zt2, W1t0, W1t1, W1t2, b1, H);
    gemm2_norm_kernel<<<N_TOK / 32, 256, 0, stream>>>(H, W2, b2, Ze);
    split2h_kernel<<<(int)(((size_t)N_TOK * DCODEX) / 1024), 256, 0, stream>>>(Ze, Zeh, Zem);
    dist_mfma_kernel<<<dim3(N_TOK / 128, KCODES / 128), 256, 0, stream>>>(Zeh, Zem, Cxh, Cxm, cn2, gbest);
    zero_scatter_kernel<<<(int)(((size_t)N_TOK * KCODES / 4) / 256), 256, 0, stream>>>(gbest, probs);
    ln_loss_kernel<<<N_TOK / 4, 256, 0, stream>>>(gbest, codex, Ze, ln_w, ln_b, Aln, loss_out);
    gemm3_kernel<<<dim3(N_TOK / 128, DMODEL / 64), 256, 0, stream>>>(Aln, Wp, bp, Zq_out);
}

// Round 8
// 684.963 us; speedup vs baseline: 1.1291x; 1.0678x over previous
//
#include <hip/hip_runtime.h>
#include <math.h>
#include <stdint.h>

#define N_TOK   8192      // B*S = 4*2048
#define DMODEL  1024
#define DCODEX  64
#define KCODES  8192

typedef _Float16 half8 __attribute__((ext_vector_type(8)));
typedef float f32x16 __attribute__((ext_vector_type(16)));
typedef float f32x4  __attribute__((ext_vector_type(4)));

union FragH { half8  h; uint2 u[2]; };
union H16   { _Float16 h; unsigned short s; };

// ---------------------------------------------------------------------------
// Flat 2-way fp16 split (hi/residual). 4 floats/thread.
__global__ __launch_bounds__(256) void split2h_kernel(const float* __restrict__ src,
                                                      unsigned short* __restrict__ p0,
                                                      unsigned short* __restrict__ p1) {
    size_t i4 = ((size_t)blockIdx.x * 256 + threadIdx.x) * 4;
    float4 v = *(const float4*)(src + i4);
    float f[4] = {v.x, v.y, v.z, v.w};
    ushort4 h0, h1;
#pragma unroll
    for (int c = 0; c < 4; ++c) {
        H16 a0, a1;
        a0.h = (_Float16)f[c];
        float r = f[c] - (float)a0.h;
        a1.h = (_Float16)r;
        ((unsigned short*)&h0)[c] = a0.s;
        ((unsigned short*)&h1)[c] = a1.s;
    }
    *(ushort4*)(p0 + i4) = h0;
    *(ushort4*)(p1 + i4) = h1;
}

// ---------------------------------------------------------------------------
// codex: fp16 2-way split + cn2[k] = ||codex[k]||^2, fused. 4 floats/thread,
// 16 threads per row of 64.
__global__ __launch_bounds__(256) void split2h_cn2_kernel(const float* __restrict__ src,
                                                          unsigned short* __restrict__ p0,
                                                          unsigned short* __restrict__ p1,
                                                          float* __restrict__ cn2) {
    const int tid = threadIdx.x;
    size_t i4 = ((size_t)blockIdx.x * 256 + tid) * 4;
    float4 v = *(const float4*)(src + i4);
    float f[4] = {v.x, v.y, v.z, v.w};
    ushort4 h0, h1;
    float s = 0.f;
#pragma unroll
    for (int c = 0; c < 4; ++c) {
        H16 a0, a1;
        a0.h = (_Float16)f[c];
        float r = f[c] - (float)a0.h;
        a1.h = (_Float16)r;
        ((unsigned short*)&h0)[c] = a0.s;
        ((unsigned short*)&h1)[c] = a1.s;
        s += f[c] * f[c];
    }
    *(ushort4*)(p0 + i4) = h0;
    *(ushort4*)(p1 + i4) = h1;
    s += __shfl_xor(s, 1, 64);
    s += __shfl_xor(s, 2, 64);
    s += __shfl_xor(s, 4, 64);
    s += __shfl_xor(s, 8, 64);
    if ((tid & 15) == 0) cn2[i4 >> 6] = s;
}

// ---------------------------------------------------------------------------
// Split W1 (k x n, fp32) into 2 transposed fp16 planes W1t_l[n][k].
__global__ __launch_bounds__(256) void split_w1_kernel(const float* __restrict__ W1,
                                                       unsigned short* __restrict__ t0,
                                                       unsigned short* __restrict__ t1) {
    __shared__ float tile[32][33];
    const int tid = threadIdx.x;
    const int k0 = blockIdx.x * 32;
    const int n0 = blockIdx.y * 32;
    {
        int i = tid >> 3, j4 = (tid & 7) * 4;
        float4 v = *(const float4*)(W1 + (size_t)(k0 + i) * DMODEL + n0 + j4);
        tile[i][j4 + 0] = v.x; tile[i][j4 + 1] = v.y;
        tile[i][j4 + 2] = v.z; tile[i][j4 + 3] = v.w;
    }
    __syncthreads();
    int n = tid >> 3, kq = (tid & 7) * 4;
    ushort4 h0, h1;
#pragma unroll
    for (int c = 0; c < 4; ++c) {
        float f = tile[kq + c][n];
        H16 a0, a1;
        a0.h = (_Float16)f;
        float r = f - (float)a0.h;
        a1.h = (_Float16)r;
        ((unsigned short*)&h0)[c] = a0.s;
        ((unsigned short*)&h1)[c] = a1.s;
    }
    size_t off = (size_t)(n0 + n) * DMODEL + k0 + kq;
    *(ushort4*)(t0 + off) = h0;
    *(ushort4*)(t1 + off) = h1;
}

// ---------------------------------------------------------------------------
// H = tanh(Z @ W1 + b1) via fp16x3 MFMA (hi/res split; hh+hm+mh).
// 128x128 block tile, 4 waves 2x2, 64x64/wave (2x2 of 32x32x16), K-tile 32.
__global__ __launch_bounds__(256) void gemm1_mfma_kernel(const unsigned short* __restrict__ Zh,
                                                         const unsigned short* __restrict__ Zm,
                                                         const unsigned short* __restrict__ W1h,
                                                         const unsigned short* __restrict__ W1m,
                                                         const float* __restrict__ b1,
                                                         float* __restrict__ H) {
    __shared__ unsigned short Ash[2][128][36];   // [level][m][k] pitch 36
    __shared__ unsigned short Bsh[2][128][36];   // [level][n][k] pitch 36
    const int tid = threadIdx.x;
    const int row0 = blockIdx.x * 128;
    const int col0 = blockIdx.y * 128;
    const int wave = tid >> 6;
    const int lane = tid & 63;
    const int lrow = lane & 31;
    const int lhalf = lane >> 5;
    const int wm = wave >> 1, wn = wave & 1;

    const unsigned short* Ap[2] = {Zh, Zm};
    const unsigned short* Bp[2] = {W1h, W1m};

    f32x16 acc[2][2];
#pragma unroll
    for (int i = 0; i < 2; ++i)
#pragma unroll
        for (int j = 0; j < 2; ++j)
#pragma unroll
            for (int r = 0; r < 16; ++r) acc[i][j][r] = 0.f;

    for (int k0 = 0; k0 < DMODEL; k0 += 32) {
        __syncthreads();   // WAR on Ash/Bsh
#pragma unroll
        for (int l = 0; l < 2; ++l) {
#pragma unroll
            for (int t = 0; t < 2; ++t) {
                int q = tid + t * 256;
                int r = q >> 2, kq = (q & 3) * 8;
                uint4 va = *(const uint4*)(Ap[l] + (size_t)(row0 + r) * DMODEL + k0 + kq);
                *(uint2*)&Ash[l][r][kq]     = make_uint2(va.x, va.y);
                *(uint2*)&Ash[l][r][kq + 4] = make_uint2(va.z, va.w);
                uint4 vb = *(const uint4*)(Bp[l] + (size_t)(col0 + r) * DMODEL + k0 + kq);
                *(uint2*)&Bsh[l][r][kq]     = make_uint2(vb.x, vb.y);
                *(uint2*)&Bsh[l][r][kq + 4] = make_uint2(vb.z, vb.w);
            }
        }
        __syncthreads();
#pragma unroll
        for (int mk = 0; mk < 2; ++mk) {
            const int kb = mk * 16 + lhalf * 8;
            FragH a0[2], a1[2], b0[2], b1[2];
#pragma unroll
            for (int ti = 0; ti < 2; ++ti) {
                int rA = wm * 64 + ti * 32 + lrow;
                a0[ti].u[0] = *(const uint2*)&Ash[0][rA][kb];
                a0[ti].u[1] = *(const uint2*)&Ash[0][rA][kb + 4];
                a1[ti].u[0] = *(const uint2*)&Ash[1][rA][kb];
                a1[ti].u[1] = *(const uint2*)&Ash[1][rA][kb + 4];
            }
#pragma unroll
            for (int tj = 0; tj < 2; ++tj) {
                int rB = wn * 64 + tj * 32 + lrow;
                b0[tj].u[0] = *(const uint2*)&Bsh[0][rB][kb];
                b0[tj].u[1] = *(const uint2*)&Bsh[0][rB][kb + 4];
                b1[tj].u[0] = *(const uint2*)&Bsh[1][rB][kb];
                b1[tj].u[1] = *(const uint2*)&Bsh[1][rB][kb + 4];
            }
#pragma unroll
            for (int ti = 0; ti < 2; ++ti)
#pragma unroll
                for (int tj = 0; tj < 2; ++tj) {
                    acc[ti][tj] = __builtin_amdgcn_mfma_f32_32x32x16_f16(a0[ti].h, b0[tj].h, acc[ti][tj], 0, 0, 0);
                    acc[ti][tj] = __builtin_amdgcn_mfma_f32_32x32x16_f16(a0[ti].h, b1[tj].h, acc[ti][tj], 0, 0, 0);
                    acc[ti][tj] = __builtin_amdgcn_mfma_f32_32x32x16_f16(a1[ti].h, b0[tj].h, acc[ti][tj], 0, 0, 0);
                }
        }
    }

    float b1v[2];
#pragma unroll
    for (int tj = 0; tj < 2; ++tj) b1v[tj] = b1[col0 + wn * 64 + tj * 32 + lrow];
#pragma unroll
    for (int ti = 0; ti < 2; ++ti)
#pragma unroll
        for (int tj = 0; tj < 2; ++tj) {
            int col = col0 + wn * 64 + tj * 32 + lrow;
#pragma unroll
            for (int r = 0; r < 16; ++r) {
                int row = row0 + wm * 64 + ti * 32 + (r & 3) + 8 * (r >> 2) + 4 * lhalf;
                H[(size_t)row * DMODEL + col] = tanhf(acc[ti][tj][r] + b1v[tj]);
            }
        }
}

// ---------------------------------------------------------------------------
// E = H @ W2 + b2 ; Ze = E / max(||E||,1e-12); also emits fp16 hi/res planes.
__global__ __launch_bounds__(256) void gemm2_norm_kernel(const float* __restrict__ H,
                                                         const float* __restrict__ W2,
                                                         const float* __restrict__ b2,
                                                         float* __restrict__ Ze,
                                                         unsigned short* __restrict__ Zeh,
                                                         unsigned short* __restrict__ Zem) {
    __shared__ float As[64][36];   // As[k][m] transposed
    __shared__ float Bs[64][68];   // Bs[k][n]
    const int tid = threadIdx.x;
    const int row0 = blockIdx.x * 32;
    const int ty = tid >> 4, tx = tid & 15;

    float acc[2][4];
#pragma unroll
    for (int i = 0; i < 2; ++i)
#pragma unroll
        for (int j = 0; j < 4; ++j) acc[i][j] = 0.f;

    for (int k0 = 0; k0 < DMODEL; k0 += 64) {
        __syncthreads();   // WAR
#pragma unroll
        for (int t = 0; t < 2; ++t) {
            int q = tid + t * 256;
            int r = q >> 4, k4 = (q & 15) * 4;
            float4 v = *(const float4*)(H + (size_t)(row0 + r) * DMODEL + k0 + k4);
            As[k4 + 0][r] = v.x; As[k4 + 1][r] = v.y;
            As[k4 + 2][r] = v.z; As[k4 + 3][r] = v.w;
        }
#pragma unroll
        for (int t = 0; t < 4; ++t) {
            int q = tid + t * 256;
            int kk = q >> 4, c4 = (q & 15) * 4;
            *(float4*)&Bs[kk][c4] = *(const float4*)(W2 + (size_t)(k0 + kk) * DCODEX + c4);
        }
        __syncthreads();
#pragma unroll
        for (int k = 0; k < 64; ++k) {
            float2 a = *(const float2*)&As[k][ty * 2];
            float4 b = *(const float4*)&Bs[k][tx * 4];
            float bw[4] = {b.x, b.y, b.z, b.w};
#pragma unroll
            for (int j = 0; j < 4; ++j) {
                acc[0][j] = fmaf(a.x, bw[j], acc[0][j]);
                acc[1][j] = fmaf(a.y, bw[j], acc[1][j]);
            }
        }
    }
    float4 b2v4 = *(const float4*)(b2 + tx * 4);
    float b2v[4] = {b2v4.x, b2v4.y, b2v4.z, b2v4.w};
#pragma unroll
    for (int i = 0; i < 2; ++i) {
        float e[4];
#pragma unroll
        for (int j = 0; j < 4; ++j) e[j] = acc[i][j] + b2v[j];
        float ss = e[0] * e[0] + e[1] * e[1] + e[2] * e[2] + e[3] * e[3];
        ss += __shfl_xor(ss, 8, 64);
        ss += __shfl_xor(ss, 4, 64);
        ss += __shfl_xor(ss, 2, 64);
        ss += __shfl_xor(ss, 1, 64);
        float nrm = fmaxf(sqrtf(ss), 1e-12f);
        float o[4];
        ushort4 h0, h1;
#pragma unroll
        for (int j = 0; j < 4; ++j) {
            o[j] = e[j] / nrm;
            H16 a0, a1;
            a0.h = (_Float16)o[j];
            float r = o[j] - (float)a0.h;
            a1.h = (_Float16)r;
            ((unsigned short*)&h0)[j] = a0.s;
            ((unsigned short*)&h1)[j] = a1.s;
        }
        size_t off = (size_t)(row0 + ty * 2 + i) * DCODEX + tx * 4;
        *(float4*)(Ze + off) = *(float4*)&o[0];
        *(ushort4*)(Zeh + off) = h0;
        *(ushort4*)(Zem + off) = h1;
    }
}

// ---------------------------------------------------------------------------
__device__ __forceinline__ unsigned fenc(float f) {
    unsigned u = __float_as_uint(f);
    return (u & 0x80000000u) ? ~u : (u | 0x80000000u);
}
__device__ __forceinline__ unsigned long long ullmin2(unsigned long long a,
                                                      unsigned long long b) {
    return a < b ? a : b;
}

// dist = cn2[k] - 2 z.c via fp16-x3 MFMA (hh+hm+mh).
// 128 tokens x 128 codes per block, grid (64,64); K=64 staged ONCE.
__global__ __launch_bounds__(256) void dist_mfma_kernel(const unsigned short* __restrict__ Zh,
                                                        const unsigned short* __restrict__ Zm,
                                                        const unsigned short* __restrict__ Ch,
                                                        const unsigned short* __restrict__ Cm,
                                                        const float* __restrict__ cn2,
                                                        unsigned long long* __restrict__ gbest) {
    __shared__ unsigned short Ash[2][128][68];   // [level][token][k] pitch 68
    __shared__ unsigned short Bsh[2][128][68];   // [level][code][k]
    __shared__ unsigned long long red[128];
    const int tid = threadIdx.x;
    const int row0 = blockIdx.x * 128;
    const int col0 = blockIdx.y * 128;
    const int wave = tid >> 6;
    const int lane = tid & 63;
    const int lrow = lane & 31;
    const int lhalf = lane >> 5;
    const int wm = wave >> 1, wn = wave & 1;

    const unsigned short* Ap[2] = {Zh, Zm};
    const unsigned short* Bp[2] = {Ch, Cm};

    if (tid < 128) red[tid] = 0xFFFFFFFFFFFFFFFFull;

#pragma unroll
    for (int l = 0; l < 2; ++l) {
#pragma unroll
        for (int t = 0; t < 4; ++t) {
            int q = tid + t * 256;
            int r = q >> 3, kq = (q & 7) * 8;
            uint4 va = *(const uint4*)(Ap[l] + (size_t)(row0 + r) * DCODEX + kq);
            *(uint2*)&Ash[l][r][kq]     = make_uint2(va.x, va.y);
            *(uint2*)&Ash[l][r][kq + 4] = make_uint2(va.z, va.w);
            uint4 vb = *(const uint4*)(Bp[l] + (size_t)(col0 + r) * DCODEX + kq);
            *(uint2*)&Bsh[l][r][kq]     = make_uint2(vb.x, vb.y);
            *(uint2*)&Bsh[l][r][kq + 4] = make_uint2(vb.z, vb.w);
        }
    }
    __syncthreads();

    f32x16 acc[2][2];
#pragma unroll
    for (int i = 0; i < 2; ++i)
#pragma unroll
        for (int j = 0; j < 2; ++j)
#pragma unroll
            for (int r = 0; r < 16; ++r) acc[i][j][r] = 0.f;

#pragma unroll
    for (int mk = 0; mk < 4; ++mk) {
        const int kb = mk * 16 + lhalf * 8;
        FragH a0[2], a1[2], b0[2], b1[2];
#pragma unroll
        for (int ti = 0; ti < 2; ++ti) {
            int rA = wm * 64 + ti * 32 + lrow;
            a0[ti].u[0] = *(const uint2*)&Ash[0][rA][kb];
            a0[ti].u[1] = *(const uint2*)&Ash[0][rA][kb + 4];
            a1[ti].u[0] = *(const uint2*)&Ash[1][rA][kb];
            a1[ti].u[1] = *(const uint2*)&Ash[1][rA][kb + 4];
        }
#pragma unroll
        for (int tj = 0; tj < 2; ++tj) {
            int rB = wn * 64 + tj * 32 + lrow;
            b0[tj].u[0] = *(const uint2*)&Bsh[0][rB][kb];
            b0[tj].u[1] = *(const uint2*)&Bsh[0][rB][kb + 4];
            b1[tj].u[0] = *(const uint2*)&Bsh[1][rB][kb];
            b1[tj].u[1] = *(const uint2*)&Bsh[1][rB][kb + 4];
        }
#pragma unroll
        for (int ti = 0; ti < 2; ++ti)
#pragma unroll
            for (int tj = 0; tj < 2; ++tj) {
                acc[ti][tj] = __builtin_amdgcn_mfma_f32_32x32x16_f16(a0[ti].h, b0[tj].h, acc[ti][tj], 0, 0, 0);
                acc[ti][tj] = __builtin_amdgcn_mfma_f32_32x32x16_f16(a0[ti].h, b1[tj].h, acc[ti][tj], 0, 0, 0);
                acc[ti][tj] = __builtin_amdgcn_mfma_f32_32x32x16_f16(a1[ti].h, b0[tj].h, acc[ti][tj], 0, 0, 0);
            }
    }

    float cnv[2];
#pragma unroll
    for (int tj = 0; tj < 2; ++tj) cnv[tj] = cn2[col0 + wn * 64 + tj * 32 + lrow];
#pragma unroll
    for (int ti = 0; ti < 2; ++ti) {
#pragma unroll
        for (int r = 0; r < 16; ++r) {
            int rloc = wm * 64 + ti * 32 + (r & 3) + 8 * (r >> 2) + 4 * lhalf;
            unsigned long long kmin = 0xFFFFFFFFFFFFFFFFull;
#pragma unroll
            for (int tj = 0; tj < 2; ++tj) {
                float dist = fmaf(-2.0f, acc[ti][tj][r], cnv[tj]);
                unsigned col = (unsigned)(col0 + wn * 64 + tj * 32 + lrow);
                unsigned long long key = ((unsigned long long)fenc(dist) << 32) | col;
                kmin = ullmin2(kmin, key);
            }
#pragma unroll
            for (int m = 1; m <= 16; m <<= 1)
                kmin = ullmin2(kmin, (unsigned long long)__shfl_xor((long long)kmin, m, 64));
            if (lrow == 0) atomicMin(&red[rloc], kmin);
        }
    }
    __syncthreads();
    if (tid < 128) atomicMin(&gbest[row0 + tid], red[tid]);
}

// ---------------------------------------------------------------------------
// probs = one_hot(argmin) : fused zero-fill + scatter, nontemporal (write-once)
__global__ __launch_bounds__(256) void zero_scatter_kernel(const unsigned long long* __restrict__ gbest,
                                                           float* __restrict__ probs) {
    size_t g = (size_t)blockIdx.x * 256 + threadIdx.x;
    int row = (int)(g >> 11);
    int c4i = (int)(g & 2047);
    unsigned id = (unsigned)(gbest[row] & 0xFFFFFFFFull);
    f32x4 v = {0.f, 0.f, 0.f, 0.f};
    if ((id >> 2) == (unsigned)c4i) v[id & 3] = 1.0f;
    __builtin_nontemporal_store(v, (f32x4*)(probs + ((size_t)row << 13) + ((size_t)c4i << 2)));
}

// ---------------------------------------------------------------------------
// STE + LayerNorm + commitment loss; writes normalized rows to Aln
__global__ __launch_bounds__(256) void ln_loss_kernel(const unsigned long long* __restrict__ gbest,
                                                      const float* __restrict__ codex,
                                                      const float* __restrict__ Ze,
                                                      const float* __restrict__ ln_w,
                                                      const float* __restrict__ ln_b,
                                                      float* __restrict__ Aln,
                                                      float* __restrict__ loss) {
    const int tid = threadIdx.x;
    const int w = tid >> 6, l = tid & 63;
    const int row = blockIdx.x * 4 + w;
    int id = (int)(unsigned)(gbest[row] & 0xFFFFFFFFull);
    float zq = codex[(size_t)id * DCODEX + l];
    float ze = Ze[(size_t)row * DCODEX + l];
    float dlt = zq - ze;
    float val = ze + dlt;   // STE forward value (reference rounding)
    float s = val;
#pragma unroll
    for (int m = 32; m >= 1; m >>= 1) s += __shfl_xor(s, m, 64);
    float mu = s * 0.015625f;
    float c = val - mu;
    float v2 = c * c;
#pragma unroll
    for (int m = 32; m >= 1; m >>= 1) v2 += __shfl_xor(v2, m, 64);
    float var = v2 * 0.015625f;
    float y = c * (1.0f / sqrtf(var + 1e-5f)) * ln_w[l] + ln_b[l];
    Aln[(size_t)row * DCODEX + l] = y;
    float d2 = dlt * dlt;
#pragma unroll
    for (int m = 32; m >= 1; m >>= 1) d2 += __shfl_xor(d2, m, 64);
    if (l == 0) atomicAdd(loss, d2 * (1.0f / 524288.0f));  // BETA=1, /(N*64)
}

// ---------------------------------------------------------------------------
// Zq = Aln @ Wp + bp : 128x64 tile, grid (64,16), 8x4/thread, K=64 one-shot
__global__ __launch_bounds__(256) void gemm3_kernel(const float* __restrict__ Aln,
                                                    const float* __restrict__ Wp,
                                                    const float* __restrict__ bp,
                                                    float* __restrict__ Zq) {
    __shared__ float As[64][132];   // As[d][token]
    __shared__ float Bs[64][68];    // Bs[d][col]
    const int tid = threadIdx.x;
    const int row0 = blockIdx.x * 128;
    const int col0 = blockIdx.y * 64;
    const int ty = tid >> 4, tx = tid & 15;

#pragma unroll
    for (int t = 0; t < 8; ++t) {
        int q = tid + t * 256;
        int r = q >> 4, d4 = (q & 15) * 4;
        float4 v = *(const float4*)(Aln + (size_t)(row0 + r) * DCODEX + d4);
        As[d4 + 0][r] = v.x; As[d4 + 1][r] = v.y;
        As[d4 + 2][r] = v.z; As[d4 + 3][r] = v.w;
    }
#pragma unroll
    for (int t = 0; t < 4; ++t) {
        int q = tid + t * 256;
        int kk = q >> 4, c4 = (q & 15) * 4;
        *(float4*)&Bs[kk][c4] = *(const float4*)(Wp + (size_t)kk * DMODEL + col0 + c4);
    }
    __syncthreads();

    float acc[8][4];
#pragma unroll
    for (int i = 0; i < 8; ++i)
#pragma unroll
        for (int j = 0; j < 4; ++j) acc[i][j] = 0.f;
#pragma unroll
    for (int k = 0; k < 64; ++k) {
        float a[8];
        *(float4*)&a[0] = *(const float4*)&As[k][ty * 4];
        *(float4*)&a[4] = *(const float4*)&As[k][64 + ty * 4];
        float4 b = *(const float4*)&Bs[k][tx * 4];
        float bw[4] = {b.x, b.y, b.z, b.w};
#pragma unroll
        for (int i = 0; i < 8; ++i)
#pragma unroll
            for (int j = 0; j < 4; ++j)
                acc[i][j] = fmaf(a[i], bw[j], acc[i][j]);
    }
    float4 bp4 = *(const float4*)(bp + col0 + tx * 4);
    float bb[4] = {bp4.x, bp4.y, bp4.z, bp4.w};
#pragma unroll
    for (int half = 0; half < 2; ++half)
#pragma unroll
        for (int i = 0; i < 4; ++i) {
            int r = row0 + half * 64 + ty * 4 + i;
            float o[4];
#pragma unroll
            for (int j = 0; j < 4; ++j) o[j] = acc[half * 4 + i][j] + bb[j];
            *(float4*)(Zq + (size_t)r * DMODEL + col0 + tx * 4) = *(float4*)&o[0];
        }
}

// ---------------------------------------------------------------------------
extern "C" void kernel_launch(void* const* d_in, const int* in_sizes, int n_in,
                              void* d_out, int out_size, void* d_ws, size_t ws_size,
                              hipStream_t stream) {
    const float* Z     = (const float*)d_in[0];
    const float* W1    = (const float*)d_in[1];
    const float* b1    = (const float*)d_in[2];
    const float* W2    = (const float*)d_in[3];
    const float* b2    = (const float*)d_in[4];
    const float* codex = (const float*)d_in[5];
    const float* ln_w  = (const float*)d_in[6];
    const float* ln_b  = (const float*)d_in[7];
    const float* Wp    = (const float*)d_in[8];
    const float* bp    = (const float*)d_in[9];

    float* out      = (float*)d_out;
    float* Zq_out   = out;                          // 8192*1024
    float* loss_out = out + (size_t)N_TOK * DMODEL; // 1
    float* probs    = loss_out + 1;                 // 8192*8192

    // workspace layout (~75 MB)
    char* ws = (char*)d_ws;
    float* H   = (float*)ws;                                   // 8192*1024 fp32
    float* Aln = H;                                            // 8192*64 (alias, H dead)
    float* Ze  = H + (size_t)N_TOK * DMODEL;                   // 8192*64
    float* cn2 = Ze + (size_t)N_TOK * DCODEX;                  // 8192
    unsigned long long* gbest = (unsigned long long*)(cn2 + KCODES);   // 8192
    unsigned short* W1h = (unsigned short*)(gbest + N_TOK);    // 2 x 1024*1024 fp16
    unsigned short* W1m = W1h + (size_t)DMODEL * DMODEL;
    unsigned short* Zth = W1m + (size_t)DMODEL * DMODEL;       // 2 x 8192*1024 fp16
    unsigned short* Ztm = Zth + (size_t)N_TOK * DMODEL;
    unsigned short* Zeh = Ztm + (size_t)N_TOK * DMODEL;        // 2 x 8192*64 fp16
    unsigned short* Zem = Zeh + (size_t)N_TOK * DCODEX;
    unsigned short* Cxh = Zem + (size_t)N_TOK * DCODEX;        // 2 x 8192*64 fp16
    unsigned short* Cxm = Cxh + (size_t)KCODES * DCODEX;

    hipMemsetAsync(loss_out, 0, sizeof(float), stream);
    hipMemsetAsync(gbest, 0xFF, (size_t)N_TOK * sizeof(unsigned long long), stream);

    split_w1_kernel<<<dim3(DMODEL / 32, DMODEL / 32), 256, 0, stream>>>(W1, W1h, W1m);
    split2h_kernel<<<(int)(((size_t)N_TOK * DMODEL) / 1024), 256, 0, stream>>>(Z, Zth, Ztm);
    split2h_cn2_kernel<<<(int)(((size_t)KCODES * DCODEX) / 1024), 256, 0, stream>>>(codex, Cxh, Cxm, cn2);
    gemm1_mfma_kernel<<<dim3(N_TOK / 128, DMODEL / 128), 256, 0, stream>>>(Zth, Ztm, W1h, W1m, b1, H);
    gemm2_norm_kernel<<<N_TOK / 32, 256, 0, stream>>>(H, W2, b2, Ze, Zeh, Zem);
    dist_mfma_kernel<<<dim3(N_TOK / 128, KCODES / 128), 256, 0, stream>>>(Zeh, Zem, Cxh, Cxm, cn2, gbest);
    zero_scatter_kernel<<<(int)(((size_t)N_TOK * KCODES / 4) / 256), 256, 0, stream>>>(gbest, probs);
    ln_loss_kernel<<<N_TOK / 4, 256, 0, stream>>>(gbest, codex, Ze, ln_w, ln_b, Aln, loss_out);
    gemm3_kernel<<<dim3(N_TOK / 128, DMODEL / 64), 256, 0, stream>>>(Aln, Wp, bp, Zq_out);
}